// Round 4
// baseline (250.675 us; speedup 1.0000x reference)
//
#include <hip/hip_runtime.h>
#include <hip/hip_bf16.h>

// B=16, C=256, H=W=96, FG=64, TFC=128. Inputs fp32 (verified R1/R2), output FP32 [16,256].
// t1 = relu(g1*stdz_o(text@w1)+be1)                [16,64,4,4]   (b1 cancels in BN)
// t2 = relu(g2*stdz_o(ConvT2d(t1,w2,s2,p1))+be2)   [16,64,8,8]   (b2 cancels in BN)
// out[b,c] = relu(max_{23x23} corr8x8(img[b,c], t2[b,c>>2])) / 64
// Inputs identified BY SIZE (six size-64 vecs in appearance order =
// b1,g1,be1,b2,g2,be2); dtype (bf16 vs fp32) auto-detected as insurance.

#define EPSF 1e-5f

typedef unsigned short u16;
typedef unsigned int u32;

static __device__ __forceinline__ float blo(u32 u) { return __uint_as_float(u << 16); }
static __device__ __forceinline__ float bhi(u32 u) { return __uint_as_float(u & 0xffff0000u); }
// wild-exponent test: decoded-as-bf16 exponent no N(0,~1) tensor produces.
static __device__ __forceinline__ int wild16(u32 u) {
    u32 e = (u >> 7) & 0xffu;
    return (e >= 134u) || (e >= 1u && e <= 90u);
}
// block-uniform: 1 if buffer at p is fp32, 0 if bf16. Samples 256 u32.
static __device__ __forceinline__ int detect_fp32(const u32* p, size_t base,
                                                  int t, float* red4) {
    u32 u = p[base + t];
    float cnt = (float)(wild16(u & 0xffffu) + wild16(u >> 16));
    #pragma unroll
    for (int m = 1; m < 64; m <<= 1) cnt += __shfl_xor(cnt, m, 64);
    if ((t & 63) == 0) red4[t >> 6] = cnt;
    __syncthreads();
    float tot = red4[0] + red4[1] + red4[2] + red4[3];
    __syncthreads();
    return tot > 64.f;
}

// ws layout (floats):
#define OFF_TEXT  0         // 2048
#define OFF_W1    2048      // 131072
#define OFF_W2    133120    // 65536
#define OFF_G1    198656    // 64
#define OFF_BE1   198720    // 64
#define OFF_G2    198784    // 64
#define OFF_BE2   198848    // 64
#define OFF_T1    198912    // 16384  [b][s][i]
#define OFF_T2    215296    // 65536  [o][b][yx]
#define CVT_N     198912

// ---- K0: convert text/w1/w2/g1/be1/g2/be2 -> fp32 in ws ------------------
__global__ __launch_bounds__(256) void k_cvt(const void* __restrict__ text,
                                             const void* __restrict__ w1,
                                             const void* __restrict__ w2,
                                             const void* __restrict__ g1,
                                             const void* __restrict__ be1,
                                             const void* __restrict__ g2,
                                             const void* __restrict__ be2,
                                             float* __restrict__ ws) {
    __shared__ float red4[4];
    int t = threadIdx.x;
    int isf32 = detect_fp32((const u32*)text, 0, t, red4);

    int eidx = (blockIdx.x * 256 + t) * 4;
    if (eidx >= CVT_N) return;
    const void* src; int soff;
    if (eidx < 2048)        { src = text; soff = eidx; }
    else if (eidx < 133120) { src = w1;   soff = eidx - 2048; }
    else if (eidx < 198656) { src = w2;   soff = eidx - 133120; }
    else {
        int k = eidx - 198656;          // 0..255
        int which = k >> 6;
        soff = k & 63;
        src = (which == 0) ? g1 : (which == 1) ? be1 : (which == 2) ? g2 : be2;
    }
    float4 v;
    if (isf32) {
        v = ((const float4*)src)[soff >> 2];
    } else {
        uint2 q = *(const uint2*)((const u16*)src + soff);
        v.x = blo(q.x); v.y = bhi(q.x); v.z = blo(q.y); v.w = bhi(q.y);
    }
    *(float4*)(ws + eidx) = v;
}

// ---- K1: t1 = relu(g1*stdz(text@w1)+be1) --------------------------------
// grid 64 (o), block 256 (b=t>>4, s=t&15). tmpl1[b*1024 + s*64 + o].
__global__ __launch_bounds__(256) void k_t1(const float* __restrict__ ws,
                                            float* __restrict__ tmpl1) {
    __shared__ float r1[4], r2[4];
    const float* textf = ws + OFF_TEXT;
    const float* w1f   = ws + OFF_W1;
    int o = blockIdx.x, t = threadIdx.x;
    int b = t >> 4, s = t & 15;
    const float* tr = textf + b * 128;
    const float* wr = w1f + o * 16 + s;
    float acc = 0.f;
    #pragma unroll 4
    for (int c = 0; c < 128; ++c)
        acc += tr[c] * wr[c * 1024];

    float s1 = acc, s2 = acc * acc;
    #pragma unroll
    for (int m = 1; m < 64; m <<= 1) {
        s1 += __shfl_xor(s1, m, 64);
        s2 += __shfl_xor(s2, m, 64);
    }
    if ((t & 63) == 0) { r1[t >> 6] = s1; r2[t >> 6] = s2; }
    __syncthreads();
    s1 = r1[0] + r1[1] + r1[2] + r1[3];
    s2 = r2[0] + r2[1] + r2[2] + r2[3];
    float mean = s1 * (1.f / 256.f);
    float var  = s2 * (1.f / 256.f) - mean * mean;
    float scale = ws[OFF_G1 + o] * rsqrtf(var + EPSF);
    float shift = ws[OFF_BE1 + o] - mean * scale;
    tmpl1[b * 1024 + s * 64 + o] = fmaxf(acc * scale + shift, 0.f);
}

// ---- K2a: ConvTranspose2d 4x4 s2 p1 : 4x4 -> 8x8 (bias cancels) ---------
// grid 1024 (b=bx>>6, o=bx&63), block 64. t2[o*1024 + b*64 + yx].
__global__ __launch_bounds__(64) void k_ct(const float* __restrict__ ws,
                                           float* __restrict__ t2) {
    __shared__ float st1[1024];      // [iy*4+ix][i]
    __shared__ float sw2[17 * 64];   // [ky*4+kx][i], row 16 = zeros
    const float* tmpl1 = ws + OFF_T1;
    const float* w2f   = ws + OFF_W2;
    int bx = blockIdx.x;
    int b = bx >> 6, o = bx & 63;
    int t = threadIdx.x;

    {
        const float4* src = (const float4*)(tmpl1 + b * 1024);
        float4* dst = (float4*)st1;
        #pragma unroll
        for (int j = 0; j < 4; ++j) dst[t + j * 64] = src[t + j * 64];
    }
    {   // thread t = input channel i; w2f[(i*64+o)*16 + k] -> sw2[k*64+i]
        const float4* wp = (const float4*)(w2f + (t * 64 + o) * 16);
        #pragma unroll
        for (int q = 0; q < 4; ++q) {
            float4 w4 = wp[q];
            sw2[(4 * q + 0) * 64 + t] = w4.x;
            sw2[(4 * q + 1) * 64 + t] = w4.y;
            sw2[(4 * q + 2) * 64 + t] = w4.z;
            sw2[(4 * q + 3) * 64 + t] = w4.w;
        }
        sw2[16 * 64 + t] = 0.f;
    }
    __syncthreads();

    int y = t >> 3, x = t & 7;
    int iy0 = (y - 1) >> 1; if (iy0 < 0) iy0 = 0;
    int ix0 = (x - 1) >> 1; if (ix0 < 0) ix0 = 0;
    float acc = 0.f;
    #pragma unroll
    for (int u = 0; u < 2; ++u) {
        int iy = iy0 + u, ky = y + 1 - 2 * iy;
        bool vy = (ky >= 0) && (iy <= 3);
        int iyc = iy > 3 ? 3 : iy;
        #pragma unroll
        for (int v = 0; v < 2; ++v) {
            int ix = ix0 + v, kx = x + 1 - 2 * ix;
            bool vx = (kx >= 0) && (ix <= 3);
            int ixc = ix > 3 ? 3 : ix;
            int arow = iyc * 4 + ixc;
            int krow = (vy && vx) ? (ky * 4 + kx) : 16;
            const float4* a4 = (const float4*)(st1 + arow * 64);
            const float4* w4 = (const float4*)(sw2 + krow * 64);
            #pragma unroll
            for (int i = 0; i < 16; ++i) {
                float4 av = a4[i], wv = w4[i];
                acc += av.x * wv.x + av.y * wv.y + av.z * wv.z + av.w * wv.w;
            }
        }
    }
    t2[o * 1024 + b * 64 + t] = acc;
}

// ---- K2b: relu(g2*stdz+be2) in-place ------------------------------------
__global__ __launch_bounds__(256) void k_bn2(float* __restrict__ t2,
                                             const float* __restrict__ ws) {
    __shared__ float r1[4], r2[4];
    int o = blockIdx.x, t = threadIdx.x;
    float4* p = (float4*)(t2 + o * 1024);
    float4 v = p[t];
    float s1 = v.x + v.y + v.z + v.w;
    float s2 = v.x * v.x + v.y * v.y + v.z * v.z + v.w * v.w;
    #pragma unroll
    for (int m = 1; m < 64; m <<= 1) {
        s1 += __shfl_xor(s1, m, 64);
        s2 += __shfl_xor(s2, m, 64);
    }
    if ((t & 63) == 0) { r1[t >> 6] = s1; r2[t >> 6] = s2; }
    __syncthreads();
    s1 = r1[0] + r1[1] + r1[2] + r1[3];
    s2 = r2[0] + r2[1] + r2[2] + r2[3];
    float mean = s1 * (1.f / 1024.f);
    float var  = s2 * (1.f / 1024.f) - mean * mean;
    float scale = ws[OFF_G2 + o] * rsqrtf(var + EPSF);
    float shift = ws[OFF_BE2 + o] - mean * scale;
    v.x = fmaxf(v.x * scale + shift, 0.f);
    v.y = fmaxf(v.y * scale + shift, 0.f);
    v.z = fmaxf(v.z * scale + shift, 0.f);
    v.w = fmaxf(v.w * scale + shift, 0.f);
    p[t] = v;
}

// ---- K3: depthwise 8x8 corr stride 4 + global max -----------------------
// grid 4096 (bc), block 256. img plane staged as fp32 in LDS (rows padded
// 96->100). Per-block dtype detection from img (random data -> safe).
__global__ __launch_bounds__(256) void k_corr(const void* __restrict__ img,
                                              const float* __restrict__ t2,
                                              float* __restrict__ out) {
    __shared__ float sf[96 * 100];
    __shared__ float sk[64];
    __shared__ float red4[4];
    int bc = blockIdx.x;
    int b = bc >> 8, c = bc & 255, o = c >> 2;
    int t = threadIdx.x;

    int isf32 = detect_fp32((const u32*)img, (size_t)bc * 4608, t, red4);

    if (t < 64) sk[t] = t2[(o * 16 + b) * 64 + t];

    if (isf32) {
        const uint4* src = (const uint4*)((const float*)img + (size_t)bc * 9216);
        #pragma unroll
        for (int j = 0; j < 9; ++j) {
            int i = t + j * 256;            // 2304 float4 groups
            uint4 q = src[i];
            int g = i * 4;
            int r = g / 96, cc = g - r * 96;
            float4* d = (float4*)(sf + r * 100 + cc);
            d[0] = make_float4(__uint_as_float(q.x), __uint_as_float(q.y),
                               __uint_as_float(q.z), __uint_as_float(q.w));
        }
    } else {
        const uint4* src = (const uint4*)((const u16*)img + (size_t)bc * 9216);
        #pragma unroll
        for (int j = 0; j < 5; ++j) {
            int i = t + j * 256;            // 1152 uint4 groups (8 bf16)
            if (i < 1152) {
                uint4 q = src[i];
                int g = i * 8;
                int r = g / 96, cc = g - r * 96;
                float4* d = (float4*)(sf + r * 100 + cc);
                d[0] = make_float4(blo(q.x), bhi(q.x), blo(q.y), bhi(q.y));
                d[1] = make_float4(blo(q.z), bhi(q.z), blo(q.w), bhi(q.w));
            }
        }
    }
    __syncthreads();

    float vmax = 0.f;
    for (int p = t; p < 529; p += 256) {
        int oy = p / 23;
        int ox = p - oy * 23;
        const float* base = sf + oy * 400 + ox * 4;
        float acc = 0.f;
        #pragma unroll
        for (int dy = 0; dy < 8; ++dy) {
            const float* r = base + dy * 100;
            float4 a0 = *(const float4*)r;
            float4 a1 = *(const float4*)(r + 4);
            const float* kr = sk + dy * 8;
            acc += a0.x * kr[0] + a0.y * kr[1] + a0.z * kr[2] + a0.w * kr[3];
            acc += a1.x * kr[4] + a1.y * kr[5] + a1.z * kr[6] + a1.w * kr[7];
        }
        vmax = fmaxf(vmax, acc);
    }
    #pragma unroll
    for (int m = 1; m < 64; m <<= 1) vmax = fmaxf(vmax, __shfl_xor(vmax, m, 64));
    __syncthreads();
    if ((t & 63) == 0) red4[t >> 6] = vmax;
    __syncthreads();
    if (t == 0) {
        float r = fmaxf(fmaxf(red4[0], red4[1]), fmaxf(red4[2], red4[3]));
        out[bc] = fmaxf(r, 0.f) * (1.f / 64.f);
    }
}

extern "C" void kernel_launch(void* const* d_in, const int* in_sizes, int n_in,
                              void* d_out, int out_size, void* d_ws, size_t ws_size,
                              hipStream_t stream) {
    const void* img = nullptr; const void* text = nullptr;
    const void* w1 = nullptr;  const void* w2 = nullptr;
    const void* v64[6] = {nullptr, nullptr, nullptr, nullptr, nullptr, nullptr};
    int nv = 0;
    for (int i = 0; i < n_in; ++i) {
        int s = in_sizes[i];
        if      (s == 37748736) img  = d_in[i];
        else if (s == 2048)     text = d_in[i];
        else if (s == 131072)   w1   = d_in[i];
        else if (s == 65536)    w2   = d_in[i];
        else if (s == 64 && nv < 6) v64[nv++] = d_in[i];
    }
    // appearance order: b1, gamma1, beta1, b2, gamma2, beta2
    const void* g1  = v64[1]; const void* be1 = v64[2];
    const void* g2  = v64[4]; const void* be2 = v64[5];

    float* ws = (float*)d_ws;
    float* tmpl1 = ws + OFF_T1;
    float* t2    = ws + OFF_T2;
    float* out = (float*)d_out;

    k_cvt <<<195,  256, 0, stream>>>(text, w1, w2, g1, be1, g2, be2, ws);
    k_t1  <<<64,   256, 0, stream>>>(ws, tmpl1);
    k_ct  <<<1024, 64,  0, stream>>>(ws, t2);
    k_bn2 <<<64,   256, 0, stream>>>(t2, ws);
    k_corr<<<4096, 256, 0, stream>>>(img, t2, out);
}

// Round 5
// 237.338 us; speedup vs baseline: 1.0562x; 1.0562x over previous
//
#include <hip/hip_runtime.h>

// B=16, C=256, H=W=96, FG=64, TFC=128. Inputs fp32, output fp32 [16,256].
// t1 = relu(g1*stdz_o(text@w1)+be1)                [16,64,4,4]  (b1 cancels in BN)
// t2 = relu(g2*stdz_o(ConvT2d(t1,w2,s2,p1))+be2)   [16,64,8,8]  (b2 cancels in BN)
// out[b,c] = relu(max_{23x23} corr8x8(img[b,c], t2[b,c>>2])) / 64
// Inputs identified BY SIZE; six size-64 vecs in appearance order = b1,g1,be1,b2,g2,be2.

#define EPSF 1e-5f

// ---- K1: t1 = relu(g1*stdz(text@w1)+be1) --------------------------------
// grid 64 (o), block 256 (b=t>>4, s=t&15). tmpl1[b*1024 + s*64 + o].
// text staged transposed [c][b] stride 17; w1 slice [c][s] stride 17.
__global__ __launch_bounds__(256) void k_t1(const float* __restrict__ textf,
                                            const float* __restrict__ w1f,
                                            const float* __restrict__ g1,
                                            const float* __restrict__ be1,
                                            float* __restrict__ tmpl1) {
    __shared__ float stext[128 * 17];
    __shared__ float sw1[128 * 17];
    __shared__ float r1[4], r2[4];
    int o = blockIdx.x, t = threadIdx.x;

    #pragma unroll
    for (int j = 0; j < 2; ++j) {               // text: 512 float4, coalesced
        int i4 = t + 256 * j;
        float4 v = ((const float4*)textf)[i4];
        int e = i4 * 4, b = e >> 7, c = e & 127;
        stext[(c + 0) * 17 + b] = v.x;
        stext[(c + 1) * 17 + b] = v.y;
        stext[(c + 2) * 17 + b] = v.z;
        stext[(c + 3) * 17 + b] = v.w;
    }
    #pragma unroll
    for (int j = 0; j < 2; ++j) {               // w1 slice: c=t>>2(+64j), q=t&3
        int c = (t >> 2) + 64 * j, q = t & 3;
        float4 v = *(const float4*)(w1f + c * 1024 + o * 16 + q * 4);
        sw1[c * 17 + q * 4 + 0] = v.x;
        sw1[c * 17 + q * 4 + 1] = v.y;
        sw1[c * 17 + q * 4 + 2] = v.z;
        sw1[c * 17 + q * 4 + 3] = v.w;
    }
    __syncthreads();

    int b = t >> 4, s = t & 15;
    float acc = 0.f;
    #pragma unroll 8
    for (int c = 0; c < 128; ++c)
        acc += stext[c * 17 + b] * sw1[c * 17 + s];

    float s1 = acc, s2 = acc * acc;
    #pragma unroll
    for (int m = 1; m < 64; m <<= 1) {
        s1 += __shfl_xor(s1, m, 64);
        s2 += __shfl_xor(s2, m, 64);
    }
    if ((t & 63) == 0) { r1[t >> 6] = s1; r2[t >> 6] = s2; }
    __syncthreads();
    s1 = r1[0] + r1[1] + r1[2] + r1[3];
    s2 = r2[0] + r2[1] + r2[2] + r2[3];
    float mean = s1 * (1.f / 256.f);
    float var  = s2 * (1.f / 256.f) - mean * mean;
    float scale = g1[o] * rsqrtf(var + EPSF);
    float shift = be1[o] - mean * scale;
    tmpl1[b * 1024 + s * 64 + o] = fmaxf(acc * scale + shift, 0.f);
}

// ---- K2: ConvT2d(4x4,s2,p1) + BN2 + ReLU, fused -------------------------
// grid 64 (o), block 512. Each thread: yx=t&63, bq=t>>6 (wave-uniform),
// computes outputs for b=2bq and 2bq+1 (w-quad register-shared).
// LDS rows padded to stride 68 (=4 mod 32 banks -> <=2-way, free).
__global__ __launch_bounds__(512) void k_ctbn(const float* __restrict__ tmpl1,
                                              const float* __restrict__ w2f,
                                              const float* __restrict__ g2,
                                              const float* __restrict__ be2,
                                              float* __restrict__ t2) {
    __shared__ float st1[256 * 68];     // [(b*16+s)][i], stride 68
    __shared__ float sw2[17 * 68];      // [krow][i], row 16 = zeros
    __shared__ float r1[8], r2[8];
    int o = blockIdx.x, t = threadIdx.x;

    #pragma unroll
    for (int j = 0; j < 8; ++j) {       // tmpl1: 4096 float4
        int i4 = t + 512 * j;
        float4 v = ((const float4*)tmpl1)[i4];
        int e = i4 * 4;
        int row = e >> 6, col = e & 63;
        *(float4*)(st1 + row * 68 + col) = v;
    }
    if (t < 256) {                      // w2 slice: i=t>>2, q=t&3
        int i = t >> 2, q = t & 3;
        float4 v = *(const float4*)(w2f + (i * 64 + o) * 16 + q * 4);
        sw2[(q * 4 + 0) * 68 + i] = v.x;
        sw2[(q * 4 + 1) * 68 + i] = v.y;
        sw2[(q * 4 + 2) * 68 + i] = v.z;
        sw2[(q * 4 + 3) * 68 + i] = v.w;
    }
    if (t < 68) sw2[16 * 68 + t] = 0.f;
    __syncthreads();

    int yx = t & 63, bq = t >> 6;
    int y = yx >> 3, x = yx & 7;
    int iy0 = (y - 1) >> 1; if (iy0 < 0) iy0 = 0;
    int ix0 = (x - 1) >> 1; if (ix0 < 0) ix0 = 0;
    float acc0 = 0.f, acc1 = 0.f;
    #pragma unroll
    for (int u = 0; u < 2; ++u) {
        int iy = iy0 + u, ky = y + 1 - 2 * iy;
        bool vy = (ky >= 0) && (iy <= 3);
        int iyc = iy > 3 ? 3 : iy;
        #pragma unroll
        for (int v = 0; v < 2; ++v) {
            int ix = ix0 + v, kx = x + 1 - 2 * ix;
            bool vx = (kx >= 0) && (ix <= 3);
            int ixc = ix > 3 ? 3 : ix;
            int arow = iyc * 4 + ixc;
            int krow = (vy && vx) ? (ky * 4 + kx) : 16;
            const float* a0 = st1 + ((bq * 2 + 0) * 16 + arow) * 68;
            const float* a1 = st1 + ((bq * 2 + 1) * 16 + arow) * 68;
            const float* w  = sw2 + krow * 68;
            #pragma unroll
            for (int i = 0; i < 16; ++i) {
                float4 wv  = *(const float4*)(w  + i * 4);
                float4 av0 = *(const float4*)(a0 + i * 4);
                float4 av1 = *(const float4*)(a1 + i * 4);
                acc0 += av0.x * wv.x + av0.y * wv.y + av0.z * wv.z + av0.w * wv.w;
                acc1 += av1.x * wv.x + av1.y * wv.y + av1.z * wv.z + av1.w * wv.w;
            }
        }
    }

    float s1 = acc0 + acc1, s2 = acc0 * acc0 + acc1 * acc1;
    #pragma unroll
    for (int m = 1; m < 64; m <<= 1) {
        s1 += __shfl_xor(s1, m, 64);
        s2 += __shfl_xor(s2, m, 64);
    }
    if ((t & 63) == 0) { r1[t >> 6] = s1; r2[t >> 6] = s2; }
    __syncthreads();
    s1 = 0.f; s2 = 0.f;
    #pragma unroll
    for (int k = 0; k < 8; ++k) { s1 += r1[k]; s2 += r2[k]; }
    float mean = s1 * (1.f / 1024.f);
    float var  = s2 * (1.f / 1024.f) - mean * mean;
    float scale = g2[o] * rsqrtf(var + EPSF);
    float shift = be2[o] - mean * scale;
    t2[o * 1024 + (bq * 2 + 0) * 64 + yx] = fmaxf(acc0 * scale + shift, 0.f);
    t2[o * 1024 + (bq * 2 + 1) * 64 + yx] = fmaxf(acc1 * scale + shift, 0.f);
}

// ---- K3: depthwise 8x8 corr stride 4 + global max -----------------------
// grid 4096 (bc), block 512. img plane -> LDS fp32, rows padded 96->100.
__global__ __launch_bounds__(512) void k_corr(const float* __restrict__ img,
                                              const float* __restrict__ t2,
                                              float* __restrict__ out) {
    __shared__ float sf[96 * 100];
    __shared__ float sk[64];
    __shared__ float red[8];
    int bc = blockIdx.x;
    int b = bc >> 8, o = (bc & 255) >> 2;
    int t = threadIdx.x;

    if (t < 64) sk[t] = t2[(o * 16 + b) * 64 + t];

    const float4* src = (const float4*)(img + (size_t)bc * 9216);
    #pragma unroll
    for (int j = 0; j < 5; ++j) {
        int i = t + j * 512;                 // 2304 float4 groups
        if (i < 2304) {
            float4 v = src[i];
            int g = i * 4;
            int r = g / 96, cc = g - r * 96;
            *(float4*)(sf + r * 100 + cc) = v;
        }
    }
    __syncthreads();

    float vmax = 0.f;
    for (int p = t; p < 529; p += 512) {
        int oy = p / 23;
        int ox = p - oy * 23;
        const float* base = sf + oy * 400 + ox * 4;
        float acc = 0.f;
        #pragma unroll
        for (int dy = 0; dy < 8; ++dy) {
            const float* r = base + dy * 100;
            float4 a0 = *(const float4*)r;
            float4 a1 = *(const float4*)(r + 4);
            const float* kr = sk + dy * 8;
            acc += a0.x * kr[0] + a0.y * kr[1] + a0.z * kr[2] + a0.w * kr[3];
            acc += a1.x * kr[4] + a1.y * kr[5] + a1.z * kr[6] + a1.w * kr[7];
        }
        vmax = fmaxf(vmax, acc);
    }
    #pragma unroll
    for (int m = 1; m < 64; m <<= 1) vmax = fmaxf(vmax, __shfl_xor(vmax, m, 64));
    if ((t & 63) == 0) red[t >> 6] = vmax;
    __syncthreads();
    if (t == 0) {
        float r = red[0];
        #pragma unroll
        for (int k = 1; k < 8; ++k) r = fmaxf(r, red[k]);
        out[bc] = fmaxf(r, 0.f) * (1.f / 64.f);
    }
}

extern "C" void kernel_launch(void* const* d_in, const int* in_sizes, int n_in,
                              void* d_out, int out_size, void* d_ws, size_t ws_size,
                              hipStream_t stream) {
    const float* img = nullptr; const float* text = nullptr;
    const float* w1 = nullptr;  const float* w2 = nullptr;
    const float* v64[6] = {nullptr, nullptr, nullptr, nullptr, nullptr, nullptr};
    int nv = 0;
    for (int i = 0; i < n_in; ++i) {
        int s = in_sizes[i];
        if      (s == 37748736) img  = (const float*)d_in[i];
        else if (s == 2048)     text = (const float*)d_in[i];
        else if (s == 131072)   w1   = (const float*)d_in[i];
        else if (s == 65536)    w2   = (const float*)d_in[i];
        else if (s == 64 && nv < 6) v64[nv++] = (const float*)d_in[i];
    }
    // appearance order: b1, gamma1, beta1, b2, gamma2, beta2
    const float* g1  = v64[1]; const float* be1 = v64[2];
    const float* g2  = v64[4]; const float* be2 = v64[5];

    float* ws = (float*)d_ws;
    float* tmpl1 = ws;              // 16384 floats  [b][s][i]
    float* t2    = ws + 16384;      // 65536 floats  [o][b][yx]
    float* out = (float*)d_out;

    k_t1  <<<64,   256, 0, stream>>>(text, w1, g1, be1, tmpl1);
    k_ctbn<<<64,   512, 0, stream>>>(tmpl1, w2, g2, be2, t2);
    k_corr<<<4096, 512, 0, stream>>>(img, t2, out);
}

// Round 6
// 237.003 us; speedup vs baseline: 1.0577x; 1.0014x over previous
//
#include <hip/hip_runtime.h>

// B=16, C=256, H=W=96, FG=64, TFC=128. Inputs fp32, output fp32 [16,256].
// t1 = relu(g1*stdz_o(text@w1)+be1)                [16,64,4,4]  (b1 cancels in BN)
// t2 = relu(g2*stdz_o(ConvT2d(t1,w2,s2,p1))+be2)   [16,64,8,8]  (b2 cancels in BN)
// out[b,c] = relu(max_{23x23} corr8x8(img[b,c], t2[b,c>>2])) / 64
// Inputs identified BY SIZE; six size-64 vecs in appearance order = b1,g1,be1,b2,g2,be2.

#define EPSF 1e-5f

// ---- K1: t1 = relu(g1*stdz(text@w1)+be1) --------------------------------
// grid 64 (o), block 256 (b=t>>4, s=t&15). tmpl1[b*1024 + s*64 + o].
__global__ __launch_bounds__(256) void k_t1(const float* __restrict__ textf,
                                            const float* __restrict__ w1f,
                                            const float* __restrict__ g1,
                                            const float* __restrict__ be1,
                                            float* __restrict__ tmpl1) {
    __shared__ float stext[128 * 17];
    __shared__ float sw1[128 * 17];
    __shared__ float r1[4], r2[4];
    int o = blockIdx.x, t = threadIdx.x;

    #pragma unroll
    for (int j = 0; j < 2; ++j) {               // text: 512 float4, coalesced
        int i4 = t + 256 * j;
        float4 v = ((const float4*)textf)[i4];
        int e = i4 * 4, b = e >> 7, c = e & 127;
        stext[(c + 0) * 17 + b] = v.x;
        stext[(c + 1) * 17 + b] = v.y;
        stext[(c + 2) * 17 + b] = v.z;
        stext[(c + 3) * 17 + b] = v.w;
    }
    #pragma unroll
    for (int j = 0; j < 2; ++j) {               // w1 slice: c=t>>2(+64j), q=t&3
        int c = (t >> 2) + 64 * j, q = t & 3;
        float4 v = *(const float4*)(w1f + c * 1024 + o * 16 + q * 4);
        sw1[c * 17 + q * 4 + 0] = v.x;
        sw1[c * 17 + q * 4 + 1] = v.y;
        sw1[c * 17 + q * 4 + 2] = v.z;
        sw1[c * 17 + q * 4 + 3] = v.w;
    }
    __syncthreads();

    int b = t >> 4, s = t & 15;
    float acc = 0.f;
    #pragma unroll 8
    for (int c = 0; c < 128; ++c)
        acc += stext[c * 17 + b] * sw1[c * 17 + s];

    float s1 = acc, s2 = acc * acc;
    #pragma unroll
    for (int m = 1; m < 64; m <<= 1) {
        s1 += __shfl_xor(s1, m, 64);
        s2 += __shfl_xor(s2, m, 64);
    }
    if ((t & 63) == 0) { r1[t >> 6] = s1; r2[t >> 6] = s2; }
    __syncthreads();
    s1 = r1[0] + r1[1] + r1[2] + r1[3];
    s2 = r2[0] + r2[1] + r2[2] + r2[3];
    float mean = s1 * (1.f / 256.f);
    float var  = s2 * (1.f / 256.f) - mean * mean;
    float scale = g1[o] * rsqrtf(var + EPSF);
    float shift = be1[o] - mean * scale;
    tmpl1[b * 1024 + s * 64 + o] = fmaxf(acc * scale + shift, 0.f);
}

// ---- K2: ConvT2d(4x4,s2,p1) + BN2 + ReLU, fused -------------------------
// grid 64 (o), block 256. Thread: yx=t&63, bq=t>>6 in [0,4); computes
// outputs for b = 4bq..4bq+3 (w-quad amortized over 4 batches ->
// 1.25 LDS float4 reads per output-quad vs 1.5 at 2-way).
// LDS rows padded to stride 68 (=4 mod 32 banks -> <=2-way, free).
__global__ __launch_bounds__(256) void k_ctbn(const float* __restrict__ tmpl1,
                                              const float* __restrict__ w2f,
                                              const float* __restrict__ g2,
                                              const float* __restrict__ be2,
                                              float* __restrict__ t2) {
    __shared__ float st1[256 * 68];     // [(b*16+s)][i], stride 68
    __shared__ float sw2[17 * 68];      // [krow][i], row 16 = zeros
    __shared__ float r1[4], r2[4];
    int o = blockIdx.x, t = threadIdx.x;

    #pragma unroll
    for (int j = 0; j < 16; ++j) {      // tmpl1: 4096 float4
        int i4 = t + 256 * j;
        float4 v = ((const float4*)tmpl1)[i4];
        int e = i4 * 4;
        int row = e >> 6, col = e & 63;
        *(float4*)(st1 + row * 68 + col) = v;
    }
    {                                   // w2 slice: i=t>>2, q=t&3
        int i = t >> 2, q = t & 3;
        float4 v = *(const float4*)(w2f + (i * 64 + o) * 16 + q * 4);
        sw2[(q * 4 + 0) * 68 + i] = v.x;
        sw2[(q * 4 + 1) * 68 + i] = v.y;
        sw2[(q * 4 + 2) * 68 + i] = v.z;
        sw2[(q * 4 + 3) * 68 + i] = v.w;
    }
    if (t < 68) sw2[16 * 68 + t] = 0.f;
    __syncthreads();

    int yx = t & 63, bq = t >> 6;
    int y = yx >> 3, x = yx & 7;
    int iy0 = (y - 1) >> 1; if (iy0 < 0) iy0 = 0;
    int ix0 = (x - 1) >> 1; if (ix0 < 0) ix0 = 0;
    float acc[4] = {0.f, 0.f, 0.f, 0.f};
    #pragma unroll
    for (int u = 0; u < 2; ++u) {
        int iy = iy0 + u, ky = y + 1 - 2 * iy;
        bool vy = (ky >= 0) && (iy <= 3);
        int iyc = iy > 3 ? 3 : iy;
        #pragma unroll
        for (int v = 0; v < 2; ++v) {
            int ix = ix0 + v, kx = x + 1 - 2 * ix;
            bool vx = (kx >= 0) && (ix <= 3);
            int ixc = ix > 3 ? 3 : ix;
            int arow = iyc * 4 + ixc;
            int krow = (vy && vx) ? (ky * 4 + kx) : 16;
            const float* w = sw2 + krow * 68;
            #pragma unroll
            for (int i = 0; i < 16; ++i) {
                float4 wv = *(const float4*)(w + i * 4);
                #pragma unroll
                for (int bb = 0; bb < 4; ++bb) {
                    const float4 av = *(const float4*)(st1 +
                        ((bq * 4 + bb) * 16 + arow) * 68 + i * 4);
                    acc[bb] += av.x * wv.x + av.y * wv.y
                             + av.z * wv.z + av.w * wv.w;
                }
            }
        }
    }

    float s1 = acc[0] + acc[1] + acc[2] + acc[3];
    float s2 = acc[0] * acc[0] + acc[1] * acc[1]
             + acc[2] * acc[2] + acc[3] * acc[3];
    #pragma unroll
    for (int m = 1; m < 64; m <<= 1) {
        s1 += __shfl_xor(s1, m, 64);
        s2 += __shfl_xor(s2, m, 64);
    }
    if ((t & 63) == 0) { r1[t >> 6] = s1; r2[t >> 6] = s2; }
    __syncthreads();
    s1 = r1[0] + r1[1] + r1[2] + r1[3];
    s2 = r2[0] + r2[1] + r2[2] + r2[3];
    float mean = s1 * (1.f / 1024.f);
    float var  = s2 * (1.f / 1024.f) - mean * mean;
    float scale = g2[o] * rsqrtf(var + EPSF);
    float shift = be2[o] - mean * scale;
    #pragma unroll
    for (int bb = 0; bb < 4; ++bb)
        t2[o * 1024 + (bq * 4 + bb) * 64 + yx] =
            fmaxf(acc[bb] * scale + shift, 0.f);
}

// ---- K3: depthwise 8x8 corr stride 4 + global max -----------------------
// grid 4096 (bc), block 512. img plane -> LDS fp32, rows padded 96->100.
// HBM-bound: 151 MB read once = ~22 us floor at 6.9 TB/s achieved.
__global__ __launch_bounds__(512) void k_corr(const float* __restrict__ img,
                                              const float* __restrict__ t2,
                                              float* __restrict__ out) {
    __shared__ float sf[96 * 100];
    __shared__ float sk[64];
    __shared__ float red[8];
    int bc = blockIdx.x;
    int b = bc >> 8, o = (bc & 255) >> 2;
    int t = threadIdx.x;

    if (t < 64) sk[t] = t2[(o * 16 + b) * 64 + t];

    const float4* src = (const float4*)(img + (size_t)bc * 9216);
    #pragma unroll
    for (int j = 0; j < 5; ++j) {
        int i = t + j * 512;                 // 2304 float4 groups
        if (i < 2304) {
            float4 v = src[i];
            int g = i * 4;
            int r = g / 96, cc = g - r * 96;
            *(float4*)(sf + r * 100 + cc) = v;
        }
    }
    __syncthreads();

    float vmax = 0.f;
    for (int p = t; p < 529; p += 512) {
        int oy = p / 23;
        int ox = p - oy * 23;
        const float* base = sf + oy * 400 + ox * 4;
        float acc = 0.f;
        #pragma unroll
        for (int dy = 0; dy < 8; ++dy) {
            const float* r = base + dy * 100;
            float4 a0 = *(const float4*)r;
            float4 a1 = *(const float4*)(r + 4);
            const float* kr = sk + dy * 8;
            acc += a0.x * kr[0] + a0.y * kr[1] + a0.z * kr[2] + a0.w * kr[3];
            acc += a1.x * kr[4] + a1.y * kr[5] + a1.z * kr[6] + a1.w * kr[7];
        }
        vmax = fmaxf(vmax, acc);
    }
    #pragma unroll
    for (int m = 1; m < 64; m <<= 1) vmax = fmaxf(vmax, __shfl_xor(vmax, m, 64));
    if ((t & 63) == 0) red[t >> 6] = vmax;
    __syncthreads();
    if (t == 0) {
        float r = red[0];
        #pragma unroll
        for (int k = 1; k < 8; ++k) r = fmaxf(r, red[k]);
        out[bc] = fmaxf(r, 0.f) * (1.f / 64.f);
    }
}

extern "C" void kernel_launch(void* const* d_in, const int* in_sizes, int n_in,
                              void* d_out, int out_size, void* d_ws, size_t ws_size,
                              hipStream_t stream) {
    const float* img = nullptr; const float* text = nullptr;
    const float* w1 = nullptr;  const float* w2 = nullptr;
    const float* v64[6] = {nullptr, nullptr, nullptr, nullptr, nullptr, nullptr};
    int nv = 0;
    for (int i = 0; i < n_in; ++i) {
        int s = in_sizes[i];
        if      (s == 37748736) img  = (const float*)d_in[i];
        else if (s == 2048)     text = (const float*)d_in[i];
        else if (s == 131072)   w1   = (const float*)d_in[i];
        else if (s == 65536)    w2   = (const float*)d_in[i];
        else if (s == 64 && nv < 6) v64[nv++] = (const float*)d_in[i];
    }
    // appearance order: b1, gamma1, beta1, b2, gamma2, beta2
    const float* g1  = v64[1]; const float* be1 = v64[2];
    const float* g2  = v64[4]; const float* be2 = v64[5];

    float* ws = (float*)d_ws;
    float* tmpl1 = ws;              // 16384 floats  [b][s][i]
    float* t2    = ws + 16384;      // 65536 floats  [o][b][yx]
    float* out = (float*)d_out;

    k_t1  <<<64,   256, 0, stream>>>(text, w1, g1, be1, tmpl1);
    k_ctbn<<<64,   256, 0, stream>>>(tmpl1, w2, g2, be2, t2);
    k_corr<<<4096, 512, 0, stream>>>(img, t2, out);
}